// Round 1
// baseline (345.191 us; speedup 1.0000x reference)
//
#include <hip/hip_runtime.h>
#include <hip/hip_bf16.h>

// GCN: h1 = relu(Â (x W1) + b1); h2 = relu(Â (h1 W2) + b2);
// out = meanpool_by_graph(h2) @ Wf + bf
// Â = D^-1/2 (A + I) D^-1/2 with deg counted on edge TARGETS (col) + self loop.

#define D 128

// ---------- degree count ----------
__global__ void k_deg(const int* __restrict__ col, int* __restrict__ cnt, int E) {
    int e = blockIdx.x * blockDim.x + threadIdx.x;
    if (e < E) atomicAdd(&cnt[col[e]], 1);
}

__global__ void k_dinv(const int* __restrict__ cnt, float* __restrict__ dinv, int n) {
    int i = blockIdx.x * blockDim.x + threadIdx.x;
    if (i < n) {
        float deg = (float)(cnt[i] + 1);   // + self loop
        dinv[i] = 1.0f / sqrtf(deg);
    }
}

// ---------- exclusive scan (single block) ----------
__global__ __launch_bounds__(1024) void k_scan(const int* __restrict__ cnt,
                                               int* __restrict__ offs,
                                               int* __restrict__ cursor, int n) {
    __shared__ int smem[1024];
    __shared__ int running;
    int t = threadIdx.x;
    if (t == 0) running = 0;
    __syncthreads();
    for (int base = 0; base < n; base += 1024) {
        int i = base + t;
        int v = (i < n) ? cnt[i] : 0;
        smem[t] = v;
        __syncthreads();
        for (int off = 1; off < 1024; off <<= 1) {
            int add = (t >= off) ? smem[t - off] : 0;
            __syncthreads();
            smem[t] += add;
            __syncthreads();
        }
        int excl = smem[t] - v;
        if (i < n) {
            int o = running + excl;
            offs[i] = o;
            cursor[i] = o;
        }
        __syncthreads();
        if (t == 0) running += smem[1023];
        __syncthreads();
    }
    if (t == 0) offs[n] = running;
}

// ---------- CSR fill (edges bucketed by target) ----------
__global__ void k_fill(const int* __restrict__ ei, int* __restrict__ cursor,
                       int* __restrict__ csr, int E) {
    int e = blockIdx.x * blockDim.x + threadIdx.x;
    if (e < E) {
        int r = ei[e];        // source
        int c = ei[E + e];    // target
        int pos = atomicAdd(&cursor[c], 1);
        csr[pos] = r;
    }
}

// ---------- fp32 GEMM: C[n,128] = A[n,128] @ B[128,128] ----------
#define GR 64
__global__ __launch_bounds__(512) void k_gemm(const float* __restrict__ A,
                                              const float* __restrict__ B,
                                              float* __restrict__ C, int n) {
    __shared__ float As[GR * D];
    __shared__ float Bs[D * D];
    int tid = threadIdx.x;
    int row0 = blockIdx.x * GR;

    // stage B (16384 floats = 4096 float4)
    for (int i = tid; i < D * D / 4; i += 512)
        ((float4*)Bs)[i] = ((const float4*)B)[i];
    // stage A tile (8192 floats = 2048 float4)
    const float4* Ab = (const float4*)(A + (size_t)row0 * D);
    for (int i = tid; i < GR * D / 4; i += 512) {
        int r = row0 + (i >> 5);  // 32 float4 per row
        float4 v = make_float4(0.f, 0.f, 0.f, 0.f);
        if (r < n) v = Ab[i];
        ((float4*)As)[i] = v;
    }
    __syncthreads();

    int tx = tid & 31;   // col group: cols tx*4 .. tx*4+3
    int ty = tid >> 5;   // row group: rows ty*4 .. ty*4+3
    float acc[4][4];
#pragma unroll
    for (int j = 0; j < 4; ++j)
#pragma unroll
        for (int i = 0; i < 4; ++i) acc[j][i] = 0.f;

    const float* Asp = As + ty * 4 * D;
#pragma unroll 8
    for (int k = 0; k < D; ++k) {
        float4 b = *(const float4*)&Bs[k * D + tx * 4];
#pragma unroll
        for (int j = 0; j < 4; ++j) {
            float a = Asp[j * D + k];
            acc[j][0] += a * b.x;
            acc[j][1] += a * b.y;
            acc[j][2] += a * b.z;
            acc[j][3] += a * b.w;
        }
    }

#pragma unroll
    for (int j = 0; j < 4; ++j) {
        int r = row0 + ty * 4 + j;
        if (r < n) {
            float4 v = make_float4(acc[j][0], acc[j][1], acc[j][2], acc[j][3]);
            *(float4*)&C[(size_t)r * D + tx * 4] = v;
        }
    }
}

// ---------- aggregate + bias + relu ----------
// out[i] = relu( dinv[i] * sum_{e: col==i} h[row_e]*dinv[row_e] + h[i]*dinv[i]^2 + b )
__global__ __launch_bounds__(256) void k_agg(const float* __restrict__ h,
                                             const float* __restrict__ dinv,
                                             const int* __restrict__ offs,
                                             const int* __restrict__ csr,
                                             const float* __restrict__ bias,
                                             float* __restrict__ out, int n) {
    int node = blockIdx.x * 8 + (threadIdx.x >> 5);
    if (node >= n) return;
    int l = threadIdx.x & 31;   // 32 lanes * float4 = 128 dims

    float di = dinv[node];
    int s = offs[node], e = offs[node + 1];
    float4 acc = make_float4(0.f, 0.f, 0.f, 0.f);
    for (int p = s; p < e; ++p) {
        int r = csr[p];
        float wv = dinv[r];
        float4 hv = *(const float4*)&h[(size_t)r * D + l * 4];
        acc.x += hv.x * wv;
        acc.y += hv.y * wv;
        acc.z += hv.z * wv;
        acc.w += hv.w * wv;
    }
    float4 hs = *(const float4*)&h[(size_t)node * D + l * 4];
    float4 b4 = *(const float4*)&bias[l * 4];
    float sd = di * di;
    float o0 = acc.x * di + hs.x * sd + b4.x;
    float o1 = acc.y * di + hs.y * sd + b4.y;
    float o2 = acc.z * di + hs.z * sd + b4.z;
    float o3 = acc.w * di + hs.w * sd + b4.w;
    float4 v = make_float4(fmaxf(o0, 0.f), fmaxf(o1, 0.f), fmaxf(o2, 0.f), fmaxf(o3, 0.f));
    *(float4*)&out[(size_t)node * D + l * 4] = v;
}

// ---------- mean pool per graph (batch sorted) ----------
__global__ __launch_bounds__(128) void k_pool(const float* __restrict__ h,
                                              const int* __restrict__ batch, int n,
                                              float* __restrict__ pooled) {
    int g = blockIdx.x;
    // lower_bound(batch, g)
    int lo = 0, hi = n;
    while (lo < hi) { int m = (lo + hi) >> 1; if (batch[m] < g) lo = m + 1; else hi = m; }
    int s = lo;
    lo = s; hi = n;
    while (lo < hi) { int m = (lo + hi) >> 1; if (batch[m] < g + 1) lo = m + 1; else hi = m; }
    int e = lo;

    int d = threadIdx.x;
    float acc = 0.f;
    for (int i = s; i < e; ++i) acc += h[(size_t)i * D + d];
    float cnt = (float)(e - s);
    if (cnt < 1.f) cnt = 1.f;
    pooled[g * D + d] = acc / cnt;
}

// ---------- final linear: out[G,128] = pooled @ Wf + bf ----------
__global__ __launch_bounds__(128) void k_final(const float* __restrict__ P,
                                               const float* __restrict__ Wf,
                                               const float* __restrict__ bf,
                                               float* __restrict__ out) {
    __shared__ float pr[D];
    int g = blockIdx.x;
    int c = threadIdx.x;
    pr[c] = P[g * D + c];
    __syncthreads();
    float acc = bf[c];
#pragma unroll 8
    for (int k = 0; k < D; ++k) acc += pr[k] * Wf[k * D + c];
    out[g * D + c] = acc;
}

extern "C" void kernel_launch(void* const* d_in, const int* in_sizes, int n_in,
                              void* d_out, int out_size, void* d_ws, size_t ws_size,
                              hipStream_t stream) {
    const float* x  = (const float*)d_in[0];
    const int*   ei = (const int*)d_in[1];   // [2, E] int32
    const int*   bt = (const int*)d_in[2];   // [n] sorted graph ids
    const float* W1 = (const float*)d_in[3];
    const float* b1 = (const float*)d_in[4];
    const float* W2 = (const float*)d_in[5];
    const float* b2 = (const float*)d_in[6];
    const float* Wf = (const float*)d_in[7];
    const float* bf = (const float*)d_in[8];
    float* out = (float*)d_out;

    int n = in_sizes[2];
    int E = in_sizes[1] / 2;
    int G = out_size / D;

    // workspace bump allocator (512B aligned)
    char* w = (char*)d_ws;
    size_t off = 0;
    auto alloc = [&](size_t bytes) -> void* {
        void* p = w + off;
        off = (off + bytes + 511) & ~(size_t)511;
        return p;
    };
    int*   degcnt = (int*)alloc((size_t)n * 4);
    int*   cursor = (int*)alloc((size_t)n * 4);
    int*   offs   = (int*)alloc((size_t)(n + 1) * 4);
    float* dinv   = (float*)alloc((size_t)n * 4);
    int*   csr    = (int*)alloc((size_t)E * 4);
    float* hw     = (float*)alloc((size_t)n * D * 4);
    float* ha     = (float*)alloc((size_t)n * D * 4);
    float* pooled = (float*)alloc((size_t)G * D * 4);

    hipMemsetAsync(degcnt, 0, (size_t)n * 4, stream);

    int eb = (E + 255) / 256;
    int nb = (n + 255) / 256;
    k_deg<<<eb, 256, 0, stream>>>(ei + E, degcnt, E);
    k_dinv<<<nb, 256, 0, stream>>>(degcnt, dinv, n);
    k_scan<<<1, 1024, 0, stream>>>(degcnt, offs, cursor, n);
    k_fill<<<eb, 256, 0, stream>>>(ei, cursor, csr, E);

    int gb = (n + GR - 1) / GR;
    int ab = (n + 7) / 8;

    // layer 1
    k_gemm<<<gb, 512, 0, stream>>>(x, W1, hw, n);
    k_agg<<<ab, 256, 0, stream>>>(hw, dinv, offs, csr, b1, ha, n);
    // layer 2
    k_gemm<<<gb, 512, 0, stream>>>(ha, W2, hw, n);
    k_agg<<<ab, 256, 0, stream>>>(hw, dinv, offs, csr, b2, ha, n);
    // pool + final
    k_pool<<<G, 128, 0, stream>>>(ha, bt, n, pooled);
    k_final<<<G, 128, 0, stream>>>(pooled, Wf, bf, out);
}

// Round 2
// 270.086 us; speedup vs baseline: 1.2781x; 1.2781x over previous
//
#include <hip/hip_runtime.h>
#include <hip/hip_bf16.h>

// GCN: h1 = relu(Â (x W1) + b1); h2 = relu(Â (h1 W2) + b2);
// out = meanpool_by_graph(h2) @ Wf + bf
// Â = D^-1/2 (A + I) D^-1/2 with deg counted on edge TARGETS (col) + self loop.

#define D 128

// ---------- degree count ----------
__global__ void k_deg(const int* __restrict__ col, int* __restrict__ cnt, int E) {
    int e = blockIdx.x * blockDim.x + threadIdx.x;
    if (e < E) atomicAdd(&cnt[col[e]], 1);
}

__global__ void k_dinv(const int* __restrict__ cnt, float* __restrict__ dinv, int n) {
    int i = blockIdx.x * blockDim.x + threadIdx.x;
    if (i < n) {
        float deg = (float)(cnt[i] + 1);   // + self loop
        dinv[i] = 1.0f / sqrtf(deg);
    }
}

// ---------- two-level exclusive scan over cnt[n] ----------
// level 1: per-block (1024 elems) partial sums
__global__ __launch_bounds__(256) void k_scan_partial(const int* __restrict__ cnt,
                                                      int* __restrict__ partial, int n) {
    int t = threadIdx.x;
    int base = blockIdx.x * 1024 + t * 4;
    int s = 0;
#pragma unroll
    for (int j = 0; j < 4; ++j) {
        int i = base + j;
        if (i < n) s += cnt[i];
    }
#pragma unroll
    for (int o = 32; o > 0; o >>= 1) s += __shfl_down(s, o, 64);
    __shared__ int ws[4];
    if ((t & 63) == 0) ws[t >> 6] = s;
    __syncthreads();
    if (t == 0) partial[blockIdx.x] = ws[0] + ws[1] + ws[2] + ws[3];
}

// level 2: exclusive-prefix the (few dozen) partials in place; write offs[n]=total
__global__ void k_scan_mid(int* __restrict__ partial, int nb,
                           int* __restrict__ offs, int n) {
    if (threadIdx.x == 0 && blockIdx.x == 0) {
        int run = 0;
        for (int i = 0; i < nb; ++i) { int v = partial[i]; partial[i] = run; run += v; }
        offs[n] = run;
    }
}

// level 3: in-block exclusive scan + block prefix → offs, cursor
__global__ __launch_bounds__(256) void k_scan_final(const int* __restrict__ cnt,
                                                    const int* __restrict__ pprefix,
                                                    int* __restrict__ offs,
                                                    int* __restrict__ cursor, int n) {
    int t = threadIdx.x;
    int lane = t & 63;
    int base = blockIdx.x * 1024 + t * 4;
    int v[4];
    int s = 0;
#pragma unroll
    for (int j = 0; j < 4; ++j) {
        int i = base + j;
        v[j] = (i < n) ? cnt[i] : 0;
        s += v[j];
    }
    // inclusive wave scan of per-thread sums
    int inc = s;
#pragma unroll
    for (int o = 1; o < 64; o <<= 1) {
        int u = __shfl_up(inc, o, 64);
        if (lane >= o) inc += u;
    }
    __shared__ int wsum[4];
    if (lane == 63) wsum[t >> 6] = inc;
    __syncthreads();
    int woff = 0;
    int w = t >> 6;
    for (int k = 0; k < w; ++k) woff += wsum[k];
    int excl = woff + (inc - s) + pprefix[blockIdx.x];
#pragma unroll
    for (int j = 0; j < 4; ++j) {
        int i = base + j;
        if (i < n) { offs[i] = excl; cursor[i] = excl; }
        excl += v[j];
    }
}

// ---------- CSR fill (edges bucketed by target) ----------
__global__ void k_fill(const int* __restrict__ ei, int* __restrict__ cursor,
                       int* __restrict__ csr, int E) {
    int e = blockIdx.x * blockDim.x + threadIdx.x;
    if (e < E) {
        int r = ei[e];        // source
        int c = ei[E + e];    // target
        int pos = atomicAdd(&cursor[c], 1);
        csr[pos] = r;
    }
}

// ---------- fp32 GEMM: C[n,128] = A[n,128] @ B[128,128] ----------
#define GR 64
__global__ __launch_bounds__(512) void k_gemm(const float* __restrict__ A,
                                              const float* __restrict__ B,
                                              float* __restrict__ C, int n) {
    __shared__ float As[GR * D];
    __shared__ float Bs[D * D];
    int tid = threadIdx.x;
    int row0 = blockIdx.x * GR;

    // stage B (16384 floats = 4096 float4)
    for (int i = tid; i < D * D / 4; i += 512)
        ((float4*)Bs)[i] = ((const float4*)B)[i];
    // stage A tile (8192 floats = 2048 float4)
    const float4* Ab = (const float4*)(A + (size_t)row0 * D);
    for (int i = tid; i < GR * D / 4; i += 512) {
        int r = row0 + (i >> 5);  // 32 float4 per row
        float4 v = make_float4(0.f, 0.f, 0.f, 0.f);
        if (r < n) v = Ab[i];
        ((float4*)As)[i] = v;
    }
    __syncthreads();

    int tx = tid & 31;   // col group: cols tx*4 .. tx*4+3
    int ty = tid >> 5;   // row group: rows ty*4 .. ty*4+3
    float acc[4][4];
#pragma unroll
    for (int j = 0; j < 4; ++j)
#pragma unroll
        for (int i = 0; i < 4; ++i) acc[j][i] = 0.f;

    const float* Asp = As + ty * 4 * D;
#pragma unroll 8
    for (int k = 0; k < D; ++k) {
        float4 b = *(const float4*)&Bs[k * D + tx * 4];
#pragma unroll
        for (int j = 0; j < 4; ++j) {
            float a = Asp[j * D + k];
            acc[j][0] += a * b.x;
            acc[j][1] += a * b.y;
            acc[j][2] += a * b.z;
            acc[j][3] += a * b.w;
        }
    }

#pragma unroll
    for (int j = 0; j < 4; ++j) {
        int r = row0 + ty * 4 + j;
        if (r < n) {
            float4 v = make_float4(acc[j][0], acc[j][1], acc[j][2], acc[j][3]);
            *(float4*)&C[(size_t)r * D + tx * 4] = v;
        }
    }
}

// ---------- aggregate + bias + relu ----------
// out[i] = relu( dinv[i] * sum_{e: col==i} h[row_e]*dinv[row_e] + h[i]*dinv[i]^2 + b )
__global__ __launch_bounds__(256) void k_agg(const float* __restrict__ h,
                                             const float* __restrict__ dinv,
                                             const int* __restrict__ offs,
                                             const int* __restrict__ csr,
                                             const float* __restrict__ bias,
                                             float* __restrict__ out, int n) {
    int node = blockIdx.x * 8 + (threadIdx.x >> 5);
    if (node >= n) return;
    int l = threadIdx.x & 31;   // 32 lanes * float4 = 128 dims

    float di = dinv[node];
    int s = offs[node], e = offs[node + 1];
    float4 acc = make_float4(0.f, 0.f, 0.f, 0.f);
    for (int p = s; p < e; ++p) {
        int r = csr[p];
        float wv = dinv[r];
        float4 hv = *(const float4*)&h[(size_t)r * D + l * 4];
        acc.x += hv.x * wv;
        acc.y += hv.y * wv;
        acc.z += hv.z * wv;
        acc.w += hv.w * wv;
    }
    float4 hs = *(const float4*)&h[(size_t)node * D + l * 4];
    float4 b4 = *(const float4*)&bias[l * 4];
    float sd = di * di;
    float o0 = acc.x * di + hs.x * sd + b4.x;
    float o1 = acc.y * di + hs.y * sd + b4.y;
    float o2 = acc.z * di + hs.z * sd + b4.z;
    float o3 = acc.w * di + hs.w * sd + b4.w;
    float4 v = make_float4(fmaxf(o0, 0.f), fmaxf(o1, 0.f), fmaxf(o2, 0.f), fmaxf(o3, 0.f));
    *(float4*)&out[(size_t)node * D + l * 4] = v;
}

// ---------- mean pool per graph (batch sorted) ----------
__global__ __launch_bounds__(128) void k_pool(const float* __restrict__ h,
                                              const int* __restrict__ batch, int n,
                                              float* __restrict__ pooled) {
    int g = blockIdx.x;
    // lower_bound(batch, g)
    int lo = 0, hi = n;
    while (lo < hi) { int m = (lo + hi) >> 1; if (batch[m] < g) lo = m + 1; else hi = m; }
    int s = lo;
    lo = s; hi = n;
    while (lo < hi) { int m = (lo + hi) >> 1; if (batch[m] < g + 1) lo = m + 1; else hi = m; }
    int e = lo;

    int d = threadIdx.x;
    float acc = 0.f;
    for (int i = s; i < e; ++i) acc += h[(size_t)i * D + d];
    float cnt = (float)(e - s);
    if (cnt < 1.f) cnt = 1.f;
    pooled[g * D + d] = acc / cnt;
}

// ---------- final linear: out[G,128] = pooled @ Wf + bf ----------
__global__ __launch_bounds__(128) void k_final(const float* __restrict__ P,
                                               const float* __restrict__ Wf,
                                               const float* __restrict__ bf,
                                               float* __restrict__ out) {
    __shared__ float pr[D];
    int g = blockIdx.x;
    int c = threadIdx.x;
    pr[c] = P[g * D + c];
    __syncthreads();
    float acc = bf[c];
#pragma unroll 8
    for (int k = 0; k < D; ++k) acc += pr[k] * Wf[k * D + c];
    out[g * D + c] = acc;
}

extern "C" void kernel_launch(void* const* d_in, const int* in_sizes, int n_in,
                              void* d_out, int out_size, void* d_ws, size_t ws_size,
                              hipStream_t stream) {
    const float* x  = (const float*)d_in[0];
    const int*   ei = (const int*)d_in[1];   // [2, E] int32
    const int*   bt = (const int*)d_in[2];   // [n] sorted graph ids
    const float* W1 = (const float*)d_in[3];
    const float* b1 = (const float*)d_in[4];
    const float* W2 = (const float*)d_in[5];
    const float* b2 = (const float*)d_in[6];
    const float* Wf = (const float*)d_in[7];
    const float* bf = (const float*)d_in[8];
    float* out = (float*)d_out;

    int n = in_sizes[2];
    int E = in_sizes[1] / 2;
    int G = out_size / D;

    // workspace bump allocator (512B aligned)
    char* w = (char*)d_ws;
    size_t off = 0;
    auto alloc = [&](size_t bytes) -> void* {
        void* p = w + off;
        off = (off + bytes + 511) & ~(size_t)511;
        return p;
    };
    int*   degcnt = (int*)alloc((size_t)n * 4);
    int*   cursor = (int*)alloc((size_t)n * 4);
    int*   offs   = (int*)alloc((size_t)(n + 1) * 4);
    float* dinv   = (float*)alloc((size_t)n * 4);
    int*   csr    = (int*)alloc((size_t)E * 4);
    float* hw     = (float*)alloc((size_t)n * D * 4);
    float* ha     = (float*)alloc((size_t)n * D * 4);
    float* pooled = (float*)alloc((size_t)G * D * 4);
    int*   partial= (int*)alloc((size_t)256 * 4);

    hipMemsetAsync(degcnt, 0, (size_t)n * 4, stream);

    int eb = (E + 255) / 256;
    int nb = (n + 255) / 256;
    int sb = (n + 1023) / 1024;
    k_deg<<<eb, 256, 0, stream>>>(ei + E, degcnt, E);
    k_dinv<<<nb, 256, 0, stream>>>(degcnt, dinv, n);
    k_scan_partial<<<sb, 256, 0, stream>>>(degcnt, partial, n);
    k_scan_mid<<<1, 64, 0, stream>>>(partial, sb, offs, n);
    k_scan_final<<<sb, 256, 0, stream>>>(degcnt, partial, offs, cursor, n);
    k_fill<<<eb, 256, 0, stream>>>(ei, cursor, csr, E);

    int gb = (n + GR - 1) / GR;
    int ab = (n + 7) / 8;

    // layer 1
    k_gemm<<<gb, 512, 0, stream>>>(x, W1, hw, n);
    k_agg<<<ab, 256, 0, stream>>>(hw, dinv, offs, csr, b1, ha, n);
    // layer 2
    k_gemm<<<gb, 512, 0, stream>>>(ha, W2, hw, n);
    k_agg<<<ab, 256, 0, stream>>>(hw, dinv, offs, csr, b2, ha, n);
    // pool + final
    k_pool<<<G, 128, 0, stream>>>(ha, bt, n, pooled);
    k_final<<<G, 128, 0, stream>>>(pooled, Wf, bf, out);
}

// Round 3
// 222.578 us; speedup vs baseline: 1.5509x; 1.2134x over previous
//
#include <hip/hip_runtime.h>
#include <hip/hip_bf16.h>

// GCN: h1 = relu(Â (x W1) + b1); h2 = relu(Â (h1 W2) + b2);
// out = meanpool_by_graph(h2) @ Wf + bf
// Â = D^-1/2 (A + I) D^-1/2, deg counted on edge TARGETS + self loop.
//
// GEMMs run on MFMA via split-bf16: A ≈ Ahi + Alo, B ≈ Bhi + Blo,
// A·B ≈ Ahi·Bhi + Alo·Bhi + Ahi·Blo  (3× mfma_f32_16x16x32_bf16, fp32 acc).
// GEMM epilogue scales row i by dinv[i], so agg gathers need no dinv loads.

#define D 128

typedef __attribute__((ext_vector_type(8))) short short8;
typedef __attribute__((ext_vector_type(4))) float f32x4;

// byte offset into a K-contiguous LDS tile with 256B rows, XOR-swizzled
__device__ __forceinline__ int swz(int row, int kbyte) {
    return row * 256 + (kbyte ^ ((row & 7) << 4));
}

__device__ __forceinline__ void cvt8(const float* f, uint4& vh, uint4& vl) {
    uint h[8], l[8];
#pragma unroll
    for (int j = 0; j < 8; ++j) {
        uint ub = __float_as_uint(f[j]);
        uint hb = ub & 0xffff0000u;          // truncate to bf16-hi
        float r = f[j] - __uint_as_float(hb);  // exact residual
        h[j] = hb >> 16;
        l[j] = __float_as_uint(r) >> 16;
    }
    vh = make_uint4(h[0] | (h[1] << 16), h[2] | (h[3] << 16),
                    h[4] | (h[5] << 16), h[6] | (h[7] << 16));
    vl = make_uint4(l[0] | (l[1] << 16), l[2] | (l[3] << 16),
                    l[4] | (l[5] << 16), l[6] | (l[7] << 16));
}

// ---------- degree count ----------
__global__ void k_deg(const int* __restrict__ col, int* __restrict__ cnt, int E) {
    int e = blockIdx.x * blockDim.x + threadIdx.x;
    if (e < E) atomicAdd(&cnt[col[e]], 1);
}

__global__ void k_dinv(const int* __restrict__ cnt, float* __restrict__ dinv, int n) {
    int i = blockIdx.x * blockDim.x + threadIdx.x;
    if (i < n) dinv[i] = 1.0f / sqrtf((float)(cnt[i] + 1));
}

// ---------- two-level exclusive scan over cnt[n] ----------
__global__ __launch_bounds__(256) void k_scan_partial(const int* __restrict__ cnt,
                                                      int* __restrict__ partial, int n) {
    int t = threadIdx.x;
    int base = blockIdx.x * 1024 + t * 4;
    int s = 0;
#pragma unroll
    for (int j = 0; j < 4; ++j) {
        int i = base + j;
        if (i < n) s += cnt[i];
    }
#pragma unroll
    for (int o = 32; o > 0; o >>= 1) s += __shfl_down(s, o, 64);
    __shared__ int ws[4];
    if ((t & 63) == 0) ws[t >> 6] = s;
    __syncthreads();
    if (t == 0) partial[blockIdx.x] = ws[0] + ws[1] + ws[2] + ws[3];
}

__global__ void k_scan_mid(int* __restrict__ partial, int nb,
                           int* __restrict__ offs, int n) {
    if (threadIdx.x == 0 && blockIdx.x == 0) {
        int run = 0;
        for (int i = 0; i < nb; ++i) { int v = partial[i]; partial[i] = run; run += v; }
        offs[n] = run;
    }
}

__global__ __launch_bounds__(256) void k_scan_final(const int* __restrict__ cnt,
                                                    const int* __restrict__ pprefix,
                                                    int* __restrict__ offs,
                                                    int* __restrict__ cursor, int n) {
    int t = threadIdx.x;
    int lane = t & 63;
    int base = blockIdx.x * 1024 + t * 4;
    int v[4];
    int s = 0;
#pragma unroll
    for (int j = 0; j < 4; ++j) {
        int i = base + j;
        v[j] = (i < n) ? cnt[i] : 0;
        s += v[j];
    }
    int inc = s;
#pragma unroll
    for (int o = 1; o < 64; o <<= 1) {
        int u = __shfl_up(inc, o, 64);
        if (lane >= o) inc += u;
    }
    __shared__ int wsum[4];
    if (lane == 63) wsum[t >> 6] = inc;
    __syncthreads();
    int woff = 0;
    int w = t >> 6;
    for (int k = 0; k < w; ++k) woff += wsum[k];
    int excl = woff + (inc - s) + pprefix[blockIdx.x];
#pragma unroll
    for (int j = 0; j < 4; ++j) {
        int i = base + j;
        if (i < n) { offs[i] = excl; cursor[i] = excl; }
        excl += v[j];
    }
}

// ---------- CSR fill ----------
__global__ void k_fill(const int* __restrict__ ei, int* __restrict__ cursor,
                       int* __restrict__ csr, int E) {
    int e = blockIdx.x * blockDim.x + threadIdx.x;
    if (e < E) {
        int r = ei[e];
        int c = ei[E + e];
        int pos = atomicAdd(&cursor[c], 1);
        csr[pos] = r;
    }
}

// ---------- weight convert+transpose: W[k][n] fp32 -> Wt_hi/lo[n][k] bf16 ----------
__global__ __launch_bounds__(256) void k_wcvt(const float* __restrict__ W,
                                              ushort* __restrict__ Wt_hi,
                                              ushort* __restrict__ Wt_lo) {
    int t = blockIdx.x * 256 + threadIdx.x;   // 2048 items: 128 n-rows × 16 kchunks
    int nrow = t >> 4;
    int kc = t & 15;
    float f[8];
#pragma unroll
    for (int j = 0; j < 8; ++j) f[j] = W[(kc * 8 + j) * D + nrow];
    uint4 vh, vl;
    cvt8(f, vh, vl);
    *(uint4*)&Wt_hi[nrow * D + kc * 8] = vh;
    *(uint4*)&Wt_lo[nrow * D + kc * 8] = vl;
}

// ---------- MFMA GEMM: C[n,128] = (A[n,128] @ B) * dinv[row] ----------
// A fp32 (converted in-kernel); B pre-converted/transposed bf16 hi/lo [n][k].
#define TM 64
__global__ __launch_bounds__(256) void k_gemm(const float* __restrict__ A,
                                              const ushort* __restrict__ Bt_hi,
                                              const ushort* __restrict__ Bt_lo,
                                              const float* __restrict__ dinv,
                                              float* __restrict__ C, int n) {
    extern __shared__ char lds[];
    char* Ah = lds;                 // 16KB: 64 rows × 256B
    char* Al = lds + 16 * 1024;     // 16KB
    char* Bh = lds + 32 * 1024;     // 32KB: 128 rows × 256B
    char* Bl = lds + 64 * 1024;     // 32KB

    int tid = threadIdx.x;
    int row0 = blockIdx.x * TM;

    // stage A: 64 rows × 16 kchunks(8 floats) = 1024 items
#pragma unroll
    for (int it = tid; it < 1024; it += 256) {
        int r = it >> 4, kc = it & 15;
        int gr = row0 + r;
        float f[8] = {0.f, 0.f, 0.f, 0.f, 0.f, 0.f, 0.f, 0.f};
        if (gr < n) {
            const float4* p = (const float4*)(A + (size_t)gr * D + kc * 8);
            float4 a0 = p[0], a1 = p[1];
            f[0] = a0.x; f[1] = a0.y; f[2] = a0.z; f[3] = a0.w;
            f[4] = a1.x; f[5] = a1.y; f[6] = a1.z; f[7] = a1.w;
        }
        uint4 vh, vl;
        cvt8(f, vh, vl);
        *(uint4*)(Ah + swz(r, kc * 16)) = vh;
        *(uint4*)(Al + swz(r, kc * 16)) = vl;
    }
    // stage B: 128 rows × 16 chunks = 2048 items (bf16 already)
#pragma unroll
    for (int it = tid; it < 2048; it += 256) {
        int r = it >> 4, kc = it & 15;
        uint4 vh = *(const uint4*)(Bt_hi + r * D + kc * 8);
        uint4 vl = *(const uint4*)(Bt_lo + r * D + kc * 8);
        *(uint4*)(Bh + swz(r, kc * 16)) = vh;
        *(uint4*)(Bl + swz(r, kc * 16)) = vl;
    }
    __syncthreads();

    int wave = tid >> 6, lane = tid & 63;
    int li = lane & 15, lg = lane >> 4;
    int arow = wave * 16 + li;

    f32x4 acc[8];
#pragma unroll
    for (int i = 0; i < 8; ++i) acc[i] = (f32x4){0.f, 0.f, 0.f, 0.f};

#pragma unroll
    for (int ks = 0; ks < 4; ++ks) {
        int kb = ks * 64 + lg * 16;
        short8 ah = *(const short8*)(Ah + swz(arow, kb));
        short8 al = *(const short8*)(Al + swz(arow, kb));
#pragma unroll
        for (int nt = 0; nt < 8; ++nt) {
            short8 bh = *(const short8*)(Bh + swz(nt * 16 + li, kb));
            short8 bl = *(const short8*)(Bl + swz(nt * 16 + li, kb));
            acc[nt] = __builtin_amdgcn_mfma_f32_16x16x32_bf16(ah, bh, acc[nt], 0, 0, 0);
            acc[nt] = __builtin_amdgcn_mfma_f32_16x16x32_bf16(al, bh, acc[nt], 0, 0, 0);
            acc[nt] = __builtin_amdgcn_mfma_f32_16x16x32_bf16(ah, bl, acc[nt], 0, 0, 0);
        }
    }

    // C/D layout (m89-verified): col = lane&15, row = (lane>>4)*4 + reg
    int crow0 = row0 + wave * 16 + lg * 4;
#pragma unroll
    for (int j = 0; j < 4; ++j) {
        int gr = crow0 + j;
        if (gr < n) {
            float dv = dinv[gr];
            float* cp = C + (size_t)gr * D + li;
#pragma unroll
            for (int nt = 0; nt < 8; ++nt)
                cp[nt * 16] = acc[nt][j] * dv;
        }
    }
}

// ---------- aggregate + bias + relu ----------
// h rows are pre-scaled by dinv (GEMM epilogue).
// out[i] = relu( dinv[i] * (sum_{r in N(i)} h[r] + h[i]) + b )
__global__ __launch_bounds__(256) void k_agg(const float* __restrict__ h,
                                             const float* __restrict__ dinv,
                                             const int* __restrict__ offs,
                                             const int* __restrict__ csr,
                                             const float* __restrict__ bias,
                                             float* __restrict__ out, int n) {
    int node = blockIdx.x * 8 + (threadIdx.x >> 5);
    if (node >= n) return;
    int l = threadIdx.x & 31;

    float di = dinv[node];
    int s = offs[node], e = offs[node + 1];
    float4 acc = *(const float4*)&h[(size_t)node * D + l * 4];  // self term
    int p = s;
    for (; p + 4 <= e; p += 4) {
        int r0 = csr[p], r1 = csr[p + 1], r2 = csr[p + 2], r3 = csr[p + 3];
        float4 h0 = *(const float4*)&h[(size_t)r0 * D + l * 4];
        float4 h1 = *(const float4*)&h[(size_t)r1 * D + l * 4];
        float4 h2 = *(const float4*)&h[(size_t)r2 * D + l * 4];
        float4 h3 = *(const float4*)&h[(size_t)r3 * D + l * 4];
        acc.x += (h0.x + h1.x) + (h2.x + h3.x);
        acc.y += (h0.y + h1.y) + (h2.y + h3.y);
        acc.z += (h0.z + h1.z) + (h2.z + h3.z);
        acc.w += (h0.w + h1.w) + (h2.w + h3.w);
    }
    for (; p < e; ++p) {
        int r = csr[p];
        float4 hv = *(const float4*)&h[(size_t)r * D + l * 4];
        acc.x += hv.x; acc.y += hv.y; acc.z += hv.z; acc.w += hv.w;
    }
    float4 b4 = *(const float4*)&bias[l * 4];
    float4 v = make_float4(fmaxf(acc.x * di + b4.x, 0.f),
                           fmaxf(acc.y * di + b4.y, 0.f),
                           fmaxf(acc.z * di + b4.z, 0.f),
                           fmaxf(acc.w * di + b4.w, 0.f));
    *(float4*)&out[(size_t)node * D + l * 4] = v;
}

// ---------- mean pool per graph (batch sorted) ----------
__global__ __launch_bounds__(128) void k_pool(const float* __restrict__ h,
                                              const int* __restrict__ batch, int n,
                                              float* __restrict__ pooled) {
    int g = blockIdx.x;
    int lo = 0, hi = n;
    while (lo < hi) { int m = (lo + hi) >> 1; if (batch[m] < g) lo = m + 1; else hi = m; }
    int s = lo;
    lo = s; hi = n;
    while (lo < hi) { int m = (lo + hi) >> 1; if (batch[m] < g + 1) lo = m + 1; else hi = m; }
    int e = lo;

    int d = threadIdx.x;
    float a0 = 0.f, a1 = 0.f, a2 = 0.f, a3 = 0.f;
    int i = s;
    for (; i + 4 <= e; i += 4) {
        a0 += h[(size_t)i * D + d];
        a1 += h[(size_t)(i + 1) * D + d];
        a2 += h[(size_t)(i + 2) * D + d];
        a3 += h[(size_t)(i + 3) * D + d];
    }
    for (; i < e; ++i) a0 += h[(size_t)i * D + d];
    float acc = (a0 + a1) + (a2 + a3);
    float cnt = (float)(e - s);
    if (cnt < 1.f) cnt = 1.f;
    pooled[g * D + d] = acc / cnt;
}

// ---------- final linear ----------
__global__ __launch_bounds__(128) void k_final(const float* __restrict__ P,
                                               const float* __restrict__ Wf,
                                               const float* __restrict__ bf,
                                               float* __restrict__ out) {
    __shared__ float pr[D];
    int g = blockIdx.x;
    int c = threadIdx.x;
    pr[c] = P[g * D + c];
    __syncthreads();
    float acc = bf[c];
#pragma unroll 8
    for (int k = 0; k < D; ++k) acc += pr[k] * Wf[k * D + c];
    out[g * D + c] = acc;
}

extern "C" void kernel_launch(void* const* d_in, const int* in_sizes, int n_in,
                              void* d_out, int out_size, void* d_ws, size_t ws_size,
                              hipStream_t stream) {
    const float* x  = (const float*)d_in[0];
    const int*   ei = (const int*)d_in[1];
    const int*   bt = (const int*)d_in[2];
    const float* W1 = (const float*)d_in[3];
    const float* b1 = (const float*)d_in[4];
    const float* W2 = (const float*)d_in[5];
    const float* b2 = (const float*)d_in[6];
    const float* Wf = (const float*)d_in[7];
    const float* bf = (const float*)d_in[8];
    float* out = (float*)d_out;

    int n = in_sizes[2];
    int E = in_sizes[1] / 2;
    int G = out_size / D;

    char* w = (char*)d_ws;
    size_t off = 0;
    auto alloc = [&](size_t bytes) -> void* {
        void* p = w + off;
        off = (off + bytes + 511) & ~(size_t)511;
        return p;
    };
    int*    degcnt = (int*)alloc((size_t)n * 4);
    int*    cursor = (int*)alloc((size_t)n * 4);
    int*    offs   = (int*)alloc((size_t)(n + 1) * 4);
    float*  dinv   = (float*)alloc((size_t)n * 4);
    int*    csr    = (int*)alloc((size_t)E * 4);
    float*  hw     = (float*)alloc((size_t)n * D * 4);
    float*  ha     = (float*)alloc((size_t)n * D * 4);
    float*  pooled = (float*)alloc((size_t)G * D * 4);
    int*    partial= (int*)alloc((size_t)256 * 4);
    ushort* wt1h   = (ushort*)alloc((size_t)D * D * 2);
    ushort* wt1l   = (ushort*)alloc((size_t)D * D * 2);
    ushort* wt2h   = (ushort*)alloc((size_t)D * D * 2);
    ushort* wt2l   = (ushort*)alloc((size_t)D * D * 2);

    hipMemsetAsync(degcnt, 0, (size_t)n * 4, stream);

    int eb = (E + 255) / 256;
    int nb = (n + 255) / 256;
    int sb = (n + 1023) / 1024;
    k_deg<<<eb, 256, 0, stream>>>(ei + E, degcnt, E);
    k_dinv<<<nb, 256, 0, stream>>>(degcnt, dinv, n);
    k_scan_partial<<<sb, 256, 0, stream>>>(degcnt, partial, n);
    k_scan_mid<<<1, 64, 0, stream>>>(partial, sb, offs, n);
    k_scan_final<<<sb, 256, 0, stream>>>(degcnt, partial, offs, cursor, n);
    k_fill<<<eb, 256, 0, stream>>>(ei, cursor, csr, E);

    k_wcvt<<<8, 256, 0, stream>>>(W1, wt1h, wt1l);
    k_wcvt<<<8, 256, 0, stream>>>(W2, wt2h, wt2l);

    int gb = (n + TM - 1) / TM;
    int ab = (n + 7) / 8;
    size_t lds_bytes = 96 * 1024;

    k_gemm<<<gb, 256, lds_bytes, stream>>>(x, wt1h, wt1l, dinv, hw, n);
    k_agg<<<ab, 256, 0, stream>>>(hw, dinv, offs, csr, b1, ha, n);
    k_gemm<<<gb, 256, lds_bytes, stream>>>(ha, wt2h, wt2l, dinv, hw, n);
    k_agg<<<ab, 256, 0, stream>>>(hw, dinv, offs, csr, b2, ha, n);
    k_pool<<<G, 128, 0, stream>>>(ha, bt, n, pooled);
    k_final<<<G, 128, 0, stream>>>(pooled, Wf, bf, out);
}